// Round 12
// baseline (7158.005 us; speedup 1.0000x reference)
//
#include <hip/hip_runtime.h>
#include <math.h>

// LogSimpleSlater: A[b][i][j] = cos/sin(k_j . r_{b,i}); out[b] = log|det A_b|.
// Register LU with SHIFTED rows: 128 threads/walker, thread owns one row.
// Invariant: at step k the thread's remaining tail is x[0..127-k], pivot
// column is ALWAYS x[0] -> all register indices static; outer k loop is a
// runtime loop (#pragma unroll 1) so code stays small (no scratch, no I$
// thrash -- round-11 failure mode). Update folds the shift into the FMA:
//   x[j] = fmaf(-m, u[j], x[j+1])     (u = shifted pivot-row tail in LDS)
// Pivot rule byte-identical to round-11 (truncated-18-bit | slot | tid,
// slot-swap bookkeeping) which PASSED at absmax 6.0; FMA ops per element
// identical -> bit-identical output expected.
// NUMERICS: exact 1/p + exact logf; do NOT "improve" pivoting or use
// rcp/log2 approximations (both previously failed absmax at 8.0).

#define NN 128
#define NTH 128

__device__ __forceinline__ int imax2(int a, int b) { return a > b ? a : b; }

// max over each 16-lane DPP row; afterwards every lane holds its row's max
__device__ __forceinline__ int dpp_max16(int x) {
    int y;
    y = __builtin_amdgcn_update_dpp(0, x, 0xB1, 0xF, 0xF, true);  x = imax2(x, y); // quad_perm [1,0,3,2]
    y = __builtin_amdgcn_update_dpp(0, x, 0x4E, 0xF, 0xF, true);  x = imax2(x, y); // quad_perm [2,3,0,1]
    y = __builtin_amdgcn_update_dpp(0, x, 0x124, 0xF, 0xF, true); x = imax2(x, y); // row_ror:4
    y = __builtin_amdgcn_update_dpp(0, x, 0x128, 0xF, 0xF, true); x = imax2(x, y); // row_ror:8
    return x;
}

__global__ void __launch_bounds__(NTH)
slater_logdet(const float* __restrict__ rs,     // [B,128,3]
              const float* __restrict__ kpts,   // [128,3]
              float* __restrict__ out)          // [B]
{
    __shared__ float kp[NN * 3];
    __shared__ __align__(16) float ush[2][NN];  // shifted pivot-row tail (dbuf)
    __shared__ float pvt[2];                    // pivot value (dbuf)
    __shared__ int xch[2];                      // per-wave max-key exchange

    const int tid  = threadIdx.x;
    const int b    = blockIdx.x;
    const int lane = tid & 63;
    const int wave = tid >> 6;

    for (int idx = tid; idx < NN * 3; idx += NTH) kp[idx] = kpts[idx];
    __syncthreads();

    // ---- generate my row: x[j] = cos/sin(k_j . r_i), i = tid
    float x[NN];
    {
        const float r0 = rs[(b * NN + tid) * 3 + 0];
        const float r1 = rs[(b * NN + tid) * 3 + 1];
        const float r2 = rs[(b * NN + tid) * 3 + 2];
#pragma unroll
        for (int j = 0; j < NN; ++j) {
            const float dot = r0 * kp[3 * j] + r1 * kp[3 * j + 1] + r2 * kp[3 * j + 2];
            x[j] = ((j == 0) || (j & 1)) ? cosf(dot) : sinf(dot);
        }
    }

    int slot = tid;          // current position under the pivot permutation
    bool active = true;
    float logsum = 0.0f;

#pragma unroll 1             // runtime loop: body must stay small
    for (int k = 0; k < NN; ++k) {
        const int buf = k & 1;

        // ---- pivot: max (truncated |x[0]|, slot) lexicographic (round-11 rule)
        const int key = active
            ? (int)((__float_as_uint(fabsf(x[0])) & 0xFFFFC000u)
                    | ((unsigned)slot << 7) | (unsigned)tid)
            : 0;
        int wm = dpp_max16(key);
        wm = imax2(imax2(__builtin_amdgcn_readlane(wm, 0),
                         __builtin_amdgcn_readlane(wm, 16)),
                   imax2(__builtin_amdgcn_readlane(wm, 32),
                         __builtin_amdgcn_readlane(wm, 48)));
        if (lane == 0) xch[wave] = wm;
        __syncthreads();                                   // barrier A
        const int kmax = imax2(xch[0], xch[1]);
        const int ptid = kmax & 127;
        const int psl  = (kmax >> 7) & 127;

        // ---- transposition (k <-> psl) on slot bookkeeping
        if (slot == k) slot = psl; else if (slot == psl) slot = k;

        // ---- owner publishes pivot + shifted tail ush[j] = x[j+1], retires
        if (tid == ptid) {
            pvt[buf] = x[0];
#pragma unroll
            for (int q = 0; q < NN / 4; ++q) {
                if (4 * q <= NN - 2 - k) {                 // uniform-k predicate
                    *(float4*)&ush[buf][4 * q] = make_float4(
                        x[4 * q + 1], x[4 * q + 2], x[4 * q + 3],
                        (4 * q + 4 < NN) ? x[4 * q + 4] : 0.0f);
                }
            }
            active = false;
        }
        __syncthreads();                                   // barrier B

        const float pivot = pvt[buf];
        if (tid == 0) logsum += logf(fabsf(pivot));        // exact log

        if (k < NN - 1 && active) {
            const float invp = 1.0f / pivot;               // exact div
            const float m = x[0] * invp;
#pragma unroll
            for (int q = 0; q < NN / 4; ++q) {
                if (4 * q <= NN - 2 - k) {                 // uniform-k predicate
                    const float4 u4 = *(const float4*)&ush[buf][4 * q];  // broadcast
                    x[4 * q + 0] = fmaf(-m, u4.x, x[4 * q + 1]);
                    x[4 * q + 1] = fmaf(-m, u4.y, x[4 * q + 2]);
                    x[4 * q + 2] = fmaf(-m, u4.z, x[4 * q + 3]);
                    x[4 * q + 3] = fmaf(-m, u4.w,
                                        (4 * q + 4 < NN) ? x[4 * q + 4] : 0.0f);
                }
            }
        }
    }

    if (tid == 0) out[b] = logsum;
}

extern "C" void kernel_launch(void* const* d_in, const int* in_sizes, int n_in,
                              void* d_out, int out_size, void* d_ws, size_t ws_size,
                              hipStream_t stream) {
    const float* rs  = (const float*)d_in[0];
    const float* kpt = (const float*)d_in[1];
    float* o = (float*)d_out;
    const int B = in_sizes[0] / (NN * 3);
    hipLaunchKernelGGL(slater_logdet, dim3(B), dim3(NTH), 0, stream, rs, kpt, o);
}

// Round 13
// 2145.750 us; speedup vs baseline: 3.3359x; 3.3359x over previous
//
#include <hip/hip_runtime.h>
#include <math.h>

// LogSimpleSlater: A[b][i][j] = cos/sin(k_j . r_{b,i}); out[b] = log|det A_b|.
// Register LU, shifted rows, NO LOCAL ARRAY: the row lives in 32 named
// float4 variables (x0..x31) via macro expansion -- a local float[128]
// (rounds 11/12) is allocated to scratch by the compiler even when all
// indices are static (VGPR=16, 27GB scratch traffic). Named variables
// cannot be stack-allocated -> guaranteed VGPRs.
// Algorithm byte-identical to round-12 (PASSED, absmax 6.0):
//   invariant: pivot column is always x0.x; update folds the shift:
//     x[j] = fmaf(-m, u[j], x[j+1]),  u = shifted pivot-row tail (LDS)
//   pivot rule: max (truncated-18-bit |x0.x|, slot) lexicographic.
// NUMERICS: exact 1/p + exact logf; do NOT use rcp/log2 approximations and
// do NOT change the pivot rule (both previously failed absmax at 8.0).

#define NN 128
#define NTH 128

__device__ __forceinline__ int imax2(int a, int b) { return a > b ? a : b; }

// max over each 16-lane DPP row; afterwards every lane holds its row's max
__device__ __forceinline__ int dpp_max16(int x) {
    int y;
    y = __builtin_amdgcn_update_dpp(0, x, 0xB1, 0xF, 0xF, true);  x = imax2(x, y); // quad_perm [1,0,3,2]
    y = __builtin_amdgcn_update_dpp(0, x, 0x4E, 0xF, 0xF, true);  x = imax2(x, y); // quad_perm [2,3,0,1]
    y = __builtin_amdgcn_update_dpp(0, x, 0x124, 0xF, 0xF, true); x = imax2(x, y); // row_ror:4
    y = __builtin_amdgcn_update_dpp(0, x, 0x128, 0xF, 0xF, true); x = imax2(x, y); // row_ror:8
    return x;
}

__global__ void __launch_bounds__(NTH)
slater_logdet(const float* __restrict__ rs,     // [B,128,3]
              const float* __restrict__ kpts,   // [128,3]
              float* __restrict__ out)          // [B]
{
    __shared__ float kp[NN * 3];
    __shared__ __align__(16) float ush[2][NN];  // shifted pivot-row tail (dbuf)
    __shared__ float pvt[2];                    // pivot value (dbuf)
    __shared__ int xch[2];                      // per-wave max-key exchange

    const int tid  = threadIdx.x;
    const int b    = blockIdx.x;
    const int lane = tid & 63;
    const int wave = tid >> 6;

    for (int idx = tid; idx < NN * 3; idx += NTH) kp[idx] = kpts[idx];
    __syncthreads();

    const float r0 = rs[(b * NN + tid) * 3 + 0];
    const float r1 = rs[(b * NN + tid) * 3 + 1];
    const float r2 = rs[(b * NN + tid) * 3 + 2];

    // ---- the row, in 32 named float4s (NOT an array)
    float4 x0,  x1,  x2,  x3,  x4,  x5,  x6,  x7,
           x8,  x9,  x10, x11, x12, x13, x14, x15,
           x16, x17, x18, x19, x20, x21, x22, x23,
           x24, x25, x26, x27, x28, x29, x30, x31;

#define GEN1(J) ((((J) == 0) || ((J) & 1)) \
    ? cosf(r0 * kp[3*(J)] + r1 * kp[3*(J)+1] + r2 * kp[3*(J)+2]) \
    : sinf(r0 * kp[3*(J)] + r1 * kp[3*(J)+1] + r2 * kp[3*(J)+2]))
#define GEN4(Q) x##Q = make_float4(GEN1(4*Q+0), GEN1(4*Q+1), GEN1(4*Q+2), GEN1(4*Q+3));
    GEN4(0)  GEN4(1)  GEN4(2)  GEN4(3)  GEN4(4)  GEN4(5)  GEN4(6)  GEN4(7)
    GEN4(8)  GEN4(9)  GEN4(10) GEN4(11) GEN4(12) GEN4(13) GEN4(14) GEN4(15)
    GEN4(16) GEN4(17) GEN4(18) GEN4(19) GEN4(20) GEN4(21) GEN4(22) GEN4(23)
    GEN4(24) GEN4(25) GEN4(26) GEN4(27) GEN4(28) GEN4(29) GEN4(30) GEN4(31)

    int slot = tid;          // current position under the pivot permutation
    bool active = true;
    float logsum = 0.0f;

#pragma unroll 1             // runtime loop: body must stay small
    for (int k = 0; k < NN; ++k) {
        const int buf = k & 1;

        // ---- pivot: max (truncated |x0.x|, slot) lexicographic (round-12 rule)
        const int key = active
            ? (int)((__float_as_uint(fabsf(x0.x)) & 0xFFFFC000u)
                    | ((unsigned)slot << 7) | (unsigned)tid)
            : 0;
        int wm = dpp_max16(key);
        wm = imax2(imax2(__builtin_amdgcn_readlane(wm, 0),
                         __builtin_amdgcn_readlane(wm, 16)),
                   imax2(__builtin_amdgcn_readlane(wm, 32),
                         __builtin_amdgcn_readlane(wm, 48)));
        if (lane == 0) xch[wave] = wm;
        __syncthreads();                                   // barrier A
        const int kmax = imax2(xch[0], xch[1]);
        const int ptid = kmax & 127;
        const int psl  = (kmax >> 7) & 127;

        // ---- transposition (k <-> psl) on slot bookkeeping
        if (slot == k) slot = psl; else if (slot == psl) slot = k;

        // ---- owner publishes pivot + shifted tail ush[j] = x[j+1], retires
        if (tid == ptid) {
            pvt[buf] = x0.x;
#define PUB(Q, QN) if (4*Q <= NN - 2 - k) \
            *(float4*)&ush[buf][4*Q] = make_float4(x##Q.y, x##Q.z, x##Q.w, x##QN.x);
            PUB(0,1)   PUB(1,2)   PUB(2,3)   PUB(3,4)   PUB(4,5)   PUB(5,6)
            PUB(6,7)   PUB(7,8)   PUB(8,9)   PUB(9,10)  PUB(10,11) PUB(11,12)
            PUB(12,13) PUB(13,14) PUB(14,15) PUB(15,16) PUB(16,17) PUB(17,18)
            PUB(18,19) PUB(19,20) PUB(20,21) PUB(21,22) PUB(22,23) PUB(23,24)
            PUB(24,25) PUB(25,26) PUB(26,27) PUB(27,28) PUB(28,29) PUB(29,30)
            PUB(30,31)
            if (124 <= NN - 2 - k)
                *(float4*)&ush[buf][124] = make_float4(x31.y, x31.z, x31.w, 0.0f);
            active = false;
        }
        __syncthreads();                                   // barrier B

        const float pivot = pvt[buf];
        if (tid == 0) logsum += logf(fabsf(pivot));        // exact log

        if (k < NN - 1 && active) {
            const float invp = 1.0f / pivot;               // exact div
            const float m = x0.x * invp;
#define UPD(Q, QN) if (4*Q <= NN - 2 - k) { \
            const float4 u4 = *(const float4*)&ush[buf][4*Q]; \
            x##Q.x = fmaf(-m, u4.x, x##Q.y); \
            x##Q.y = fmaf(-m, u4.y, x##Q.z); \
            x##Q.z = fmaf(-m, u4.z, x##Q.w); \
            x##Q.w = fmaf(-m, u4.w, x##QN.x); }
            UPD(0,1)   UPD(1,2)   UPD(2,3)   UPD(3,4)   UPD(4,5)   UPD(5,6)
            UPD(6,7)   UPD(7,8)   UPD(8,9)   UPD(9,10)  UPD(10,11) UPD(11,12)
            UPD(12,13) UPD(13,14) UPD(14,15) UPD(15,16) UPD(16,17) UPD(17,18)
            UPD(18,19) UPD(19,20) UPD(20,21) UPD(21,22) UPD(22,23) UPD(23,24)
            UPD(24,25) UPD(25,26) UPD(26,27) UPD(27,28) UPD(28,29) UPD(29,30)
            UPD(30,31)
            if (124 <= NN - 2 - k) {
                const float4 u4 = *(const float4*)&ush[buf][124];
                x31.x = fmaf(-m, u4.x, x31.y);
                x31.y = fmaf(-m, u4.y, x31.z);
                x31.z = fmaf(-m, u4.z, x31.w);
                x31.w = fmaf(-m, u4.w, 0.0f);
            }
        }
    }

    if (tid == 0) out[b] = logsum;
}

extern "C" void kernel_launch(void* const* d_in, const int* in_sizes, int n_in,
                              void* d_out, int out_size, void* d_ws, size_t ws_size,
                              hipStream_t stream) {
    const float* rs  = (const float*)d_in[0];
    const float* kpt = (const float*)d_in[1];
    float* o = (float*)d_out;
    const int B = in_sizes[0] / (NN * 3);
    hipLaunchKernelGGL(slater_logdet, dim3(B), dim3(NTH), 0, stream, rs, kpt, o);
}